// Round 2
// baseline (541.975 us; speedup 1.0000x reference)
//
#include <hip/hip_runtime.h>
#include <cstdint>
#include <cstddef>

// Problem dims (fixed)
#define TOK   1024   // B*T
#define DIMX  512
#define HID   2048
#define DM    256
#define GENH  512
#define RR    64
#define O3BASE 65536 // start row of path-3 block in gen_w2 (2*R*DIM)

typedef __bf16 bf16x8 __attribute__((ext_vector_type(8)));
typedef float  f32x4  __attribute__((ext_vector_type(4)));
typedef unsigned short u16x8 __attribute__((ext_vector_type(8)));

__device__ __forceinline__ unsigned short f2bf(float f) {
  union { float f; uint32_t u; } v; v.f = f;
  return (unsigned short)((v.u + 0x7fffu + ((v.u >> 16) & 1u)) >> 16);
}
__device__ __forceinline__ float bf2f(unsigned short h) {
  union { uint32_t u; float f; } v; v.u = (uint32_t)h << 16;
  return v.f;
}
__device__ __forceinline__ float silu_f(float x) { return x / (1.f + __expf(-x)); }

// HW f32->bf16 (RNE; lowers to v_cvt_pk_bf16_f32 pairs on gfx950)
__device__ __forceinline__ u16x8 cvt8_hw(float4 a, float4 b) {
  union { __bf16 h; unsigned short u; } c;
  u16x8 r;
  c.h = (__bf16)a.x; r[0] = c.u; c.h = (__bf16)a.y; r[1] = c.u;
  c.h = (__bf16)a.z; r[2] = c.u; c.h = (__bf16)a.w; r[3] = c.u;
  c.h = (__bf16)b.x; r[4] = c.u; c.h = (__bf16)b.y; r[5] = c.u;
  c.h = (__bf16)b.z; r[6] = c.u; c.h = (__bf16)b.w; r[7] = c.u;
  return r;
}

__device__ __forceinline__ void async_copy16(const void* g, void* l) {
  __builtin_amdgcn_global_load_lds(
      (const __attribute__((address_space(1))) void*)g,
      (__attribute__((address_space(3))) void*)l, 16, 0, 0);
}

__device__ __forceinline__ void cast8(const float* __restrict__ src,
                                      unsigned short* __restrict__ dst, size_t i) {
  float4 v0 = *(const float4*)(src + i);
  float4 v1 = *(const float4*)(src + i + 4);
  ushort4 h0, h1;
  h0.x = f2bf(v0.x); h0.y = f2bf(v0.y); h0.z = f2bf(v0.z); h0.w = f2bf(v0.w);
  h1.x = f2bf(v1.x); h1.y = f2bf(v1.y); h1.z = f2bf(v1.z); h1.w = f2bf(v1.w);
  *(ushort4*)(dst + i)     = h0;
  *(ushort4*)(dst + i + 4) = h1;
}

// ---------------------------------------------------------------------------
// Stage one [ROWS x 64] bf16 tile into LDS via global_load_lds width=16,
// fetch-side XOR swizzle (chunk' = chunk ^ (row&7)) -> conflict-free b128.
// ---------------------------------------------------------------------------
template<int ROWS>
__device__ __forceinline__ void stage_tile(
    const unsigned short* __restrict__ base, size_t row0, int stride, int kofs,
    unsigned short* Ls, int tid) {
  constexpr int IT = ROWS / 32;           // 16B chunks per thread
  const int wave = tid >> 6, lane = tid & 63;
#pragma unroll
  for (int j = 0; j < IT; ++j) {
    int s   = wave * (IT * 64) + j * 64 + lane;   // linear 16B slot
    int row = s >> 3;
    int kc  = (s & 7) ^ (row & 7);                // fetch-side swizzle
    const unsigned short* g = base + (row0 + (size_t)row) * (size_t)stride + kofs + kc * 8;
    async_copy16(g, (char*)Ls + wave * (IT * 1024) + j * 1024);
  }
}

// ---------------------------------------------------------------------------
// Core: C[MF*32 x 128] = A[MF*32 x K] @ B[128 x K]^T (bf16, K-contig) via
// mfma_f32_16x16x32_bf16, 4 waves 2x2. Ends with __syncthreads().
// (Used by small GEMMs: ffn12, gemm3p.)
// ---------------------------------------------------------------------------
template<int KLEN, int MF>
__device__ __forceinline__ void mfma_tile_nt(
    const unsigned short* __restrict__ Abf, size_t a_row0, int astride,
    const unsigned short* __restrict__ Bbf, size_t b_row0, int bstride, int k0,
    unsigned short* As, unsigned short* Bs, f32x4 (&acc)[MF][4]) {
  const int tid  = threadIdx.x;
  const int lane = tid & 63;
  const int wave = tid >> 6;
  const int m0 = (wave >> 1) * (MF * 16), n0 = (wave & 1) * 64;

  for (int kk = 0; kk < KLEN; kk += 64) {
    stage_tile<MF * 32>(Abf, a_row0, astride, k0 + kk, As, tid);
    stage_tile<128>(Bbf, b_row0, bstride, k0 + kk, Bs, tid);
    __syncthreads();
#pragma unroll
    for (int ks = 0; ks < 2; ++ks) {
      int cbase = ks * 4 + (lane >> 4);
      int koff  = (cbase ^ (lane & 7)) * 8;   // row&7 == lane&7 for all frags
      bf16x8 a[MF], b[4];
#pragma unroll
      for (int mf = 0; mf < MF; ++mf)
        a[mf] = *(const bf16x8*)(As + (m0 + mf * 16 + (lane & 15)) * 64 + koff);
#pragma unroll
      for (int nf = 0; nf < 4; ++nf)
        b[nf] = *(const bf16x8*)(Bs + (n0 + nf * 16 + (lane & 15)) * 64 + koff);
#pragma unroll
      for (int mf = 0; mf < MF; ++mf)
#pragma unroll
        for (int nf = 0; nf < 4; ++nf)
          acc[mf][nf] = __builtin_amdgcn_mfma_f32_16x16x32_bf16(
              a[mf], b[nf], acc[mf][nf], 0, 0, 0);
    }
    __syncthreads();
  }
}

// ---------------------------------------------------------------------------
// Pipelined core (2-phase, T3/T4 minimum recipe): double-buffered A (async
// global_load_lds) + B (f32 source: reg-load issued one phase EARLY, cvt +
// single ds_write_b128 AFTER the MFMA cluster -> HBM/L2 latency hides under
// compute; one barrier per K-step). Ends fully synchronized.
// LDS: As = 2 * MF*32*64 shorts, Bs = 2 * 128*64 shorts.
// ---------------------------------------------------------------------------
template<int KLEN, int MF>
__device__ __forceinline__ void mfma_pipe_bf32(
    const unsigned short* __restrict__ Abf, size_t a_row0, int astride,
    const float* __restrict__ Bf, size_t b_row0, int bstride,
    unsigned short* As, unsigned short* Bs, f32x4 (&acc)[MF][4]) {
  const int tid  = threadIdx.x;
  const int lane = tid & 63;
  const int wave = tid >> 6;
  const int m0 = (wave >> 1) * (MF * 16), n0 = (wave & 1) * 64;
  constexpr int ABUF = MF * 32 * 64;   // shorts per A buffer
  constexpr int BBUF = 128 * 64;       // shorts per B buffer
  constexpr int NT   = KLEN / 64;

  float4 v[8];  // in-flight B f32 regs (statically indexed only)

  auto loadB = [&](int kk) {
#pragma unroll
    for (int jj = 0; jj < 4; ++jj) {
      int s   = wave * 256 + jj * 64 + lane;   // linear 16B slot
      int row = s >> 3;
      int kc  = (s & 7) ^ (row & 7);           // fetch-side swizzle
      const float* g = Bf + (b_row0 + (size_t)row) * (size_t)bstride + kk + kc * 8;
      v[2 * jj]     = *(const float4*)g;
      v[2 * jj + 1] = *(const float4*)(g + 4);
    }
  };
  auto writeB = [&](unsigned short* Bd) {
#pragma unroll
    for (int jj = 0; jj < 4; ++jj) {
      int s = wave * 256 + jj * 64 + lane;
      *(u16x8*)(Bd + s * 8) = cvt8_hw(v[2 * jj], v[2 * jj + 1]);  // one b128 store
    }
  };
  auto compute = [&](const unsigned short* Ab, const unsigned short* Bb) {
#pragma unroll
    for (int ks = 0; ks < 2; ++ks) {
      int cbase = ks * 4 + (lane >> 4);
      int koff  = (cbase ^ (lane & 7)) * 8;
      bf16x8 a[MF], b[4];
#pragma unroll
      for (int mf = 0; mf < MF; ++mf)
        a[mf] = *(const bf16x8*)(Ab + (m0 + mf * 16 + (lane & 15)) * 64 + koff);
#pragma unroll
      for (int nf = 0; nf < 4; ++nf)
        b[nf] = *(const bf16x8*)(Bb + (n0 + nf * 16 + (lane & 15)) * 64 + koff);
#pragma unroll
      for (int mf = 0; mf < MF; ++mf)
#pragma unroll
        for (int nf = 0; nf < 4; ++nf)
          acc[mf][nf] = __builtin_amdgcn_mfma_f32_16x16x32_bf16(
              a[mf], b[nf], acc[mf][nf], 0, 0, 0);
    }
  };

  // prologue: stage tile 0 (not hideable, once)
  stage_tile<MF * 32>(Abf, a_row0, astride, 0, As, tid);
  loadB(0);
  writeB(Bs);
  __syncthreads();

  int cur = 0;
  for (int t = 0; t < NT - 1; ++t) {
    // issue next tile's loads FIRST (A: async->LDS; B: into regs)
    stage_tile<MF * 32>(Abf, a_row0, astride, (t + 1) * 64, As + (cur ^ 1) * ABUF, tid);
    loadB((t + 1) * 64);
    // compute current tile while loads fly
    compute(As + cur * ABUF, Bs + cur * BBUF);
    // land B (vmcnt wait happens here, after the MFMA cluster)
    writeB(Bs + (cur ^ 1) * BBUF);
    __syncthreads();   // drains A's global_load_lds + makes B writes visible
    cur ^= 1;
  }
  compute(As + cur * ABUF, Bs + cur * BBUF);
  __syncthreads();     // LDS is reused by caller epilogues
}

template<int MF>
__device__ __forceinline__ void zero_accN(f32x4 (&acc)[MF][4]) {
#pragma unroll
  for (int i = 0; i < MF; ++i)
#pragma unroll
    for (int j = 0; j < 4; ++j) {
      f32x4 z = {0.f, 0.f, 0.f, 0.f};
      acc[i][j] = z;
    }
}

// ---------------------------------------------------------------------------
// prep: hg = silu(m_tok @ gen_w1^T + gen_b1) -> bf16; x -> bf16;
// also casts W1/W2/W3 to bf16 (folded to save launches).
// ---------------------------------------------------------------------------
__global__ __launch_bounds__(256) void prep_kernel(
    const float* __restrict__ x, const float* __restrict__ m_tok,
    const float* __restrict__ gen_w1, const float* __restrict__ gen_b1,
    const float* __restrict__ W1, const float* __restrict__ W2,
    const float* __restrict__ W3,
    unsigned short* __restrict__ xb, unsigned short* __restrict__ hgb,
    unsigned short* __restrict__ W1b, unsigned short* __restrict__ W2b,
    unsigned short* __restrict__ W3b) {
  __shared__ float mt[4 * DM];
  const int tid = threadIdx.x;
  const size_t t0 = (size_t)blockIdx.x * 4;
#pragma unroll
  for (int k = 0; k < 4; ++k) mt[k * 256 + tid] = m_tok[t0 * DM + k * 256 + tid];
#pragma unroll
  for (int k = 0; k < 8; ++k) {
    size_t idx = t0 * DIMX + k * 256 + tid;
    xb[idx] = f2bf(x[idx]);
  }
  // folded weight casts: 1,048,576 elems each = 2 chunks/thread each
  {
    size_t base = ((size_t)blockIdx.x * 256 + tid) * 8;
#pragma unroll
    for (int it = 0; it < 2; ++it) {
      size_t idx = base + (size_t)it * 524288;
      cast8(W1, W1b, idx);
      cast8(W2, W2b, idx);
      cast8(W3, W3b, idx);
    }
  }
  __syncthreads();
#pragma unroll
  for (int hh = 0; hh < 2; ++hh) {
    int h = hh * 256 + tid;
    float a0, a1, a2, a3;
    a0 = a1 = a2 = a3 = gen_b1[h];
    const float* wr = gen_w1 + (size_t)h * DM;
    for (int d = 0; d < DM; d += 4) {
      float4 w = *(const float4*)(wr + d);
      a0 += w.x * mt[d]       + w.y * mt[d + 1]       + w.z * mt[d + 2]       + w.w * mt[d + 3];
      a1 += w.x * mt[256 + d] + w.y * mt[256 + d + 1] + w.z * mt[256 + d + 2] + w.w * mt[256 + d + 3];
      a2 += w.x * mt[512 + d] + w.y * mt[512 + d + 1] + w.z * mt[512 + d + 2] + w.w * mt[512 + d + 3];
      a3 += w.x * mt[768 + d] + w.y * mt[768 + d + 1] + w.z * mt[768 + d + 2] + w.w * mt[768 + d + 3];
    }
    hgb[(t0 + 0) * GENH + h] = f2bf(silu_f(a0));
    hgb[(t0 + 1) * GENH + h] = f2bf(silu_f(a1));
    hgb[(t0 + 2) * GENH + h] = f2bf(silu_f(a2));
    hgb[(t0 + 3) * GENH + h] = f2bf(silu_f(a3));
  }
}

// ---------------------------------------------------------------------------
// ffn12 body: fused x@W1^T / x@W2^T + bias + silu-mul -> hb (bf16).
// Tile 32 tok x 128 o, 512 blocks. Waves 2x2 (16x64 each).
// ---------------------------------------------------------------------------
__device__ __forceinline__ void ffn12_body(
    int bx, const unsigned short* __restrict__ xb, const unsigned short* __restrict__ W1b,
    const unsigned short* __restrict__ W2b, const float* __restrict__ pb1,
    const float* __restrict__ pb2, unsigned short* __restrict__ hb,
    unsigned short* As, unsigned short* B1s, unsigned short* B2s) {
  const int tid = threadIdx.x, lane = tid & 63, wave = tid >> 6;
  const int ob = bx & 15, tb = bx >> 4;
  const size_t t0 = (size_t)tb * 32, o0 = (size_t)ob * 128;
  const int m0 = (wave >> 1) * 16, n0 = (wave & 1) * 64;

  f32x4 acc1[4], acc2[4];
#pragma unroll
  for (int j = 0; j < 4; ++j) {
    f32x4 z = {0.f, 0.f, 0.f, 0.f};
    acc1[j] = z; acc2[j] = z;
  }

  for (int kk = 0; kk < DIMX; kk += 64) {
    stage_tile<32>(xb, t0, DIMX, kk, As, tid);
    stage_tile<128>(W1b, o0, DIMX, kk, B1s, tid);
    stage_tile<128>(W2b, o0, DIMX, kk, B2s, tid);
    __syncthreads();
#pragma unroll
    for (int ks = 0; ks < 2; ++ks) {
      int cbase = ks * 4 + (lane >> 4);
      int koff  = (cbase ^ (lane & 7)) * 8;
      bf16x8 a, b1[4], b2[4];
      a = *(const bf16x8*)(As + (m0 + (lane & 15)) * 64 + koff);
#pragma unroll
      for (int nf = 0; nf < 4; ++nf) {
        b1[nf] = *(const bf16x8*)(B1s + (n0 + nf * 16 + (lane & 15)) * 64 + koff);
        b2[nf] = *(const bf16x8*)(B2s + (n0 + nf * 16 + (lane & 15)) * 64 + koff);
      }
#pragma unroll
      for (int nf = 0; nf < 4; ++nf) {
        acc1[nf] = __builtin_amdgcn_mfma_f32_16x16x32_bf16(a, b1[nf], acc1[nf], 0, 0, 0);
        acc2[nf] = __builtin_amdgcn_mfma_f32_16x16x32_bf16(a, b2[nf], acc2[nf], 0, 0, 0);
      }
    }
    __syncthreads();
  }

  const int q = lane >> 4;
  float b1v[4], b2v[4];
#pragma unroll
  for (int nf = 0; nf < 4; ++nf) {
    b1v[nf] = pb1[o0 + n0 + nf * 16 + (lane & 15)];
    b2v[nf] = pb2[o0 + n0 + nf * 16 + (lane & 15)];
  }
#pragma unroll
  for (int nf = 0; nf < 4; ++nf)
#pragma unroll
    for (int rg = 0; rg < 4; ++rg) {
      size_t trow = t0 + m0 + q * 4 + rg;
      size_t col  = o0 + n0 + nf * 16 + (lane & 15);
      float v1 = acc1[nf][rg] + b1v[nf];
      float v2 = acc2[nf][rg] + b2v[nf];
      hb[trow * HID + col] = f2bf(silu_f(v1) * v2);
    }
}

// ---------------------------------------------------------------------------
// memuv body: fused paths 1&2, B read directly from f32 gen_w2 via the
// pipelined core. Block = [128 tok x 128 o] tile; epilogue contracts vs x
// staged in LDS [128x128] bf16 with address swizzle; leaders store float4
// partials. Strip-consecutive XCD map preserved.
// ---------------------------------------------------------------------------
union SmemUV {
  struct { unsigned short As[2 * 128 * 64], Bs[2 * 128 * 64]; } ab;  // 64 KB
  struct { unsigned short Xs[128 * 128]; } ep;                       // 32 KB
};

__device__ __forceinline__ void memuv_body(
    int bx, const unsigned short* __restrict__ hgb, const float* __restrict__ gw2,
    const float* __restrict__ gen_b2, const unsigned short* __restrict__ xb,
    float* __restrict__ up, SmemUV& sm) {
  const int s8 = bx & 7, w = bx >> 3;
  const int tb = w & 7, strip = (w >> 3) * 8 + s8;   // 0..511
  const size_t o0 = (size_t)strip * 128, t0 = (size_t)tb * 128;
  const int j  = strip >> 2;        // u column (0..127)
  const int d0 = (strip & 3) * 128; // d-range within the r row

  f32x4 acc[4][4];
  zero_accN<4>(acc);
  mfma_pipe_bf32<GENH, 4>(hgb, t0, GENH, gw2, o0, GENH, sm.ab.As, sm.ab.Bs, acc);

  const int tid = threadIdx.x, lane = tid & 63, wave = tid >> 6;
  // stage x tile [128 t x 128 d] bf16 with chunk swizzle ^(((row>>2)&3)<<1)
#pragma unroll
  for (int i = 0; i < 8; ++i) {
    int qq = i * 256 + tid;         // 8-short chunks, 2048 total
    int row = qq >> 4, c = qq & 15;
    const unsigned short* src = xb + (t0 + (size_t)row) * DIMX + d0 + c * 8;
    ushort4 v0 = *(const ushort4*)src;
    ushort4 v1 = *(const ushort4*)(src + 4);
    int cs = c ^ (((row >> 2) & 3) << 1);
    unsigned short* dst = sm.ep.Xs + row * 128 + cs * 8;
    *(ushort4*)dst = v0;
    *(ushort4*)(dst + 4) = v1;
  }
  __syncthreads();

  const int m0 = (wave >> 1) * 64, n0 = (wave & 1) * 64;
  const int q = lane >> 4, l15 = lane & 15;
  float gbv[4];
#pragma unroll
  for (int i = 0; i < 4; ++i)
    gbv[i] = gen_b2[o0 + n0 + i * 16 + l15];

  const int p = (strip & 3) * 2 + (wave & 1);
  float* upd = up + (size_t)p * (128 * 1024) + (size_t)j * 1024 + t0;
#pragma unroll
  for (int mf = 0; mf < 4; ++mf) {
    f32x4 vals;
#pragma unroll
    for (int rg = 0; rg < 4; ++rg) {
      int trow = m0 + mf * 16 + q * 4 + rg;
      int swz  = ((trow >> 2) & 3) << 1;
      float val = 0.f;
#pragma unroll
      for (int nf = 0; nf < 4; ++nf) {
        int col = n0 + nf * 16 + l15;
        int idx = trow * 128 + (((col >> 3) ^ swz) << 3) + (col & 7);
        val += (acc[mf][nf][rg] + gbv[nf]) * bf2f(sm.ep.Xs[idx]);
      }
      val += __shfl_xor(val, 1);
      val += __shfl_xor(val, 2);
      val += __shfl_xor(val, 4);
      val += __shfl_xor(val, 8);
      vals[rg] = val;
    }
    if (l15 == 0)
      *(f32x4*)(upd + m0 + mf * 16 + q * 4) = vals;
  }
}

// K2 = {ffn12 (512 blocks)} ++ {memuv (4096 blocks)}: independent work,
// ffn12 hides under memuv. 512 % 8 == 0 keeps memuv's XCD strip map intact.
union SmemK2 {
  struct { unsigned short As[32 * 64], B1s[128 * 64], B2s[128 * 64]; } f; // 36 KB
  SmemUV m;                                                              // 64 KB
};

__global__ __launch_bounds__(256, 2) void k2_kernel(
    const unsigned short* __restrict__ xb, const unsigned short* __restrict__ W1b,
    const unsigned short* __restrict__ W2b, const float* __restrict__ b1,
    const float* __restrict__ b2, unsigned short* __restrict__ hb,
    const unsigned short* __restrict__ hgb, const float* __restrict__ gw2,
    const float* __restrict__ gen_b2, float* __restrict__ up) {
  __shared__ SmemK2 sm;
  const int bx = blockIdx.x;
  if (bx < 512)
    ffn12_body(bx, xb, W1b, W2b, b1, b2, hb, sm.f.As, sm.f.B1s, sm.f.B2s);
  else
    memuv_body(bx - 512, hgb, gw2, gen_b2, xb, up, sm.m);
}

// ---------------------------------------------------------------------------
// gemm3p body: yp[slice] = hb @ W3b^T (partial K), 64x128 tiles.
// 256 blocks: 16 t-tiles x 4 o-tiles x 4 K-slices (KTILE=512).
// ---------------------------------------------------------------------------
__device__ __forceinline__ void gemm3p_body(
    int bx, const unsigned short* __restrict__ hb, const unsigned short* __restrict__ W3b,
    float* __restrict__ yp, unsigned short* As, unsigned short* Bs) {
  const int slice = bx >> 6, r6 = bx & 63;
  const int ob = r6 & 3, tb = r6 >> 2;
  const size_t o0 = (size_t)ob * 128, t0 = (size_t)tb * 64;
  const int k0 = slice * 512;
  f32x4 acc[2][4];
  zero_accN<2>(acc);
  mfma_tile_nt<512, 2>(hb, t0, HID, W3b, o0, HID, k0, As, Bs, acc);

  const int tid = threadIdx.x, lane = tid & 63, wave = tid >> 6;
  const int m0 = (wave >> 1) * 32, n0 = (wave & 1) * 64;
  float* out = yp + (size_t)slice * (TOK * DIMX);
#pragma unroll
  for (int nf = 0; nf < 4; ++nf) {
    int n = n0 + nf * 16 + (lane & 15);
#pragma unroll
    for (int mf = 0; mf < 2; ++mf) {
      int mb = m0 + mf * 16 + ((lane >> 4) << 2);
#pragma unroll
      for (int rg = 0; rg < 4; ++rg)
        out[(t0 + mb + rg) * DIMX + o0 + n] = acc[mf][nf][rg];
    }
  }
}

// ---------------------------------------------------------------------------
// hmem body: u = sum of 8 partials (coalesced in t); h_mem = silu(u1)*u2.
// ---------------------------------------------------------------------------
__device__ __forceinline__ void hmem_body(int bx, const float* __restrict__ up,
                                          float* __restrict__ hm) {
  int i = bx * 256 + threadIdx.x;          // 65536
  int t = i & 1023, r = i >> 10;           // r in 0..63
  float u1 = 0.f, u2 = 0.f;
#pragma unroll
  for (int p = 0; p < 8; ++p) {
    u1 += up[(size_t)p * (128 * 1024) + (size_t)r * 1024 + t];
    u2 += up[(size_t)p * (128 * 1024) + (size_t)(64 + r) * 1024 + t];
  }
  hm[(size_t)t * RR + r] = silu_f(u1) * u2;
}

// K3 = {gemm3p (256 blocks)} ++ {hmem (256 blocks)}: independent work.
union SmemK3 {
  struct { unsigned short As[64 * 64], Bs[128 * 64]; } g;  // 24 KB
};

__global__ __launch_bounds__(256) void k3_kernel(
    const unsigned short* __restrict__ hb, const unsigned short* __restrict__ W3b,
    float* __restrict__ yp, const float* __restrict__ up, float* __restrict__ hm) {
  __shared__ SmemK3 sm;
  const int bx = blockIdx.x;
  if (bx < 256)
    gemm3p_body(bx, hb, W3b, yp, sm.g.As, sm.g.Bs);
  else
    hmem_body(bx - 256, up, hm);
}

// ---------------------------------------------------------------------------
// memy: fused path 3, B read directly from f32 gen_w2 via pipelined core.
// Epilogue contracts vs h_mem in LDS [128x64] f32 with chunk swizzle;
// single-writer y = (b3 + sum4 yp) + g*val (yreduce folded in).
// ---------------------------------------------------------------------------
union SmemY {
  struct { unsigned short As[2 * 128 * 64], Bs[2 * 128 * 64]; } ab;  // 64 KB
  struct { float Hs[128 * 64]; } ep;                                 // 32 KB
};

__global__ __launch_bounds__(256, 2) void memy_kernel(
    const unsigned short* __restrict__ hgb, const float* __restrict__ gw2,
    const float* __restrict__ gen_b2, const float* __restrict__ hmem,
    const float* __restrict__ yp, const float* __restrict__ b3,
    const float* __restrict__ mem_gate, float* __restrict__ y) {
  __shared__ SmemY sm;
  const int bx = blockIdx.x;
  const int s8 = bx & 7, w = bx >> 3;
  const int tb = w & 7, strip = (w >> 3) * 8 + s8;   // 0..255
  const size_t brow0 = (size_t)O3BASE + (size_t)strip * 128;
  const size_t t0 = (size_t)tb * 128;

  f32x4 acc[4][4];
  zero_accN<4>(acc);
  mfma_pipe_bf32<GENH, 4>(hgb, t0, GENH, gw2, brow0, GENH, sm.ab.As, sm.ab.Bs, acc);

  const int tid = threadIdx.x, lane = tid & 63, wave = tid >> 6;
  // stage h_mem tile [128 t x 64 r] f32, chunk swizzle ^(((row>>2)&3)<<2)
#pragma unroll
  for (int i = 0; i < 8; ++i) {
    int qq = i * 256 + tid;         // float4 chunks, 2048 total
    int row = qq >> 4, c = qq & 15;
    float4 v = *(const float4*)(hmem + (t0 + (size_t)row) * RR + c * 4);
    int cs = c ^ (((row >> 2) & 3) << 2);
    *(float4*)(sm.ep.Hs + row * 64 + cs * 4) = v;
  }
  __syncthreads();

  const int m0 = (wave >> 1) * 64, n0 = (wave & 1) * 64;
  const int q = lane >> 4, l15 = lane & 15;
  const float g = 1.f / (1.f + __expf(-mem_gate[0]));
  float gbv[4];
#pragma unroll
  for (int i = 0; i < 4; ++i)
    gbv[i] = gen_b2[brow0 + n0 + i * 16 + l15];

  const int d = strip * 2 + (wave & 1);
  const float b3v = b3[d];
#pragma unroll
  for (int mf = 0; mf < 4; ++mf)
#pragma unroll
    for (int rg = 0; rg < 4; ++rg) {
      int trow = m0 + mf * 16 + q * 4 + rg;
      int swz  = ((trow >> 2) & 3) << 2;
      float val = 0.f;
#pragma unroll
      for (int nf = 0; nf < 4; ++nf) {
        int r = nf * 16 + l15;
        int idx = trow * 64 + (((r >> 2) ^ swz) << 2) + (r & 3);
        val += (acc[mf][nf][rg] + gbv[nf]) * sm.ep.Hs[idx];
      }
      val += __shfl_xor(val, 1);
      val += __shfl_xor(val, 2);
      val += __shfl_xor(val, 4);
      val += __shfl_xor(val, 8);
      if (l15 == 0) {
        size_t gi = (t0 + trow) * DIMX + d;
        float base = b3v + yp[gi]
                   + yp[(size_t)1 * (TOK * DIMX) + gi]
                   + yp[(size_t)2 * (TOK * DIMX) + gi]
                   + yp[(size_t)3 * (TOK * DIMX) + gi];
        y[gi] = base + g * val;
      }
    }
}

// ---------------------------------------------------------------------------
extern "C" void kernel_launch(void* const* d_in, const int* in_sizes, int n_in,
                              void* d_out, int out_size, void* d_ws, size_t ws_size,
                              hipStream_t stream) {
  const float* x        = (const float*)d_in[0];
  const float* m_tok    = (const float*)d_in[1];
  const float* W1       = (const float*)d_in[2];
  const float* W2       = (const float*)d_in[3];
  const float* W3       = (const float*)d_in[4];
  const float* b1       = (const float*)d_in[5];
  const float* b2       = (const float*)d_in[6];
  const float* b3       = (const float*)d_in[7];
  const float* gen_w1   = (const float*)d_in[8];
  const float* gen_b1   = (const float*)d_in[9];
  const float* gen_w2   = (const float*)d_in[10];
  const float* gen_b2   = (const float*)d_in[11];
  const float* mem_gate = (const float*)d_in[12];
  float* y = (float*)d_out;

  char* ws = (char*)d_ws;
#define KB(v) ((size_t)(v) << 10)
  unsigned short* xb  = (unsigned short*)(ws);               // 1 MB
  unsigned short* hgb = (unsigned short*)(ws + KB(1024));    // 1 MB
  unsigned short* hb  = (unsigned short*)(ws + KB(2048));    // 4 MB
  float* up  = (float*)(ws + KB(6144));                      // 4 MB
  float* hm  = (float*)(ws + KB(10240));                     // 512 KB
  float* yp  = (float*)(ws + KB(10752));                     // 8 MB (4 slices)
  unsigned short* W1b = (unsigned short*)(ws + KB(21248));   // 2 MB
  unsigned short* W2b = (unsigned short*)(ws + KB(23296));   // 2 MB
  unsigned short* W3b = (unsigned short*)(ws + KB(25344));   // 2 MB
#undef KB

  // K1: casts + hypernet layer-1
  prep_kernel<<<256, 256, 0, stream>>>(x, m_tok, gen_w1, gen_b1, W1, W2, W3,
                                       xb, hgb, W1b, W2b, W3b);
  // K2: base-FFN up-proj (hidden under) memory-path u/v GEMM (pipelined f32-B)
  k2_kernel<<<512 + 4096, 256, 0, stream>>>(xb, W1b, W2b, b1, b2, hb,
                                            hgb, gen_w2, gen_b2, up);
  // K3: base-FFN down-proj partials (hidden over) h_mem reduction
  k3_kernel<<<256 + 256, 256, 0, stream>>>(hb, W3b, yp, up, hm);
  // K4: path-3 GEMM + epilogue, yreduce folded into the single-writer store
  memy_kernel<<<2048, 256, 0, stream>>>(hgb, gen_w2, gen_b2, hm, yp, b3,
                                        mem_gate, y);
}

// Round 3
// 493.780 us; speedup vs baseline: 1.0976x; 1.0976x over previous
//
#include <hip/hip_runtime.h>
#include <cstdint>
#include <cstddef>

// Problem dims (fixed)
#define TOK   1024   // B*T
#define DIMX  512
#define HID   2048
#define DM    256
#define GENH  512
#define RR    64
#define O3BASE 65536 // start row of path-3 block in gen_w2 (2*R*DIM)

typedef __bf16 bf16x8 __attribute__((ext_vector_type(8)));
typedef float  f32x4  __attribute__((ext_vector_type(4)));
typedef unsigned short u16x8 __attribute__((ext_vector_type(8)));

__device__ __forceinline__ unsigned short f2bf(float f) {
  union { float f; uint32_t u; } v; v.f = f;
  return (unsigned short)((v.u + 0x7fffu + ((v.u >> 16) & 1u)) >> 16);
}
__device__ __forceinline__ float bf2f(unsigned short h) {
  union { uint32_t u; float f; } v; v.u = (uint32_t)h << 16;
  return v.f;
}
__device__ __forceinline__ float silu_f(float x) { return x / (1.f + __expf(-x)); }

// HW f32->bf16 (RNE; lowers to v_cvt_pk_bf16_f32 pairs on gfx950)
__device__ __forceinline__ u16x8 cvt8_hw(float4 a, float4 b) {
  union { __bf16 h; unsigned short u; } c;
  u16x8 r;
  c.h = (__bf16)a.x; r[0] = c.u; c.h = (__bf16)a.y; r[1] = c.u;
  c.h = (__bf16)a.z; r[2] = c.u; c.h = (__bf16)a.w; r[3] = c.u;
  c.h = (__bf16)b.x; r[4] = c.u; c.h = (__bf16)b.y; r[5] = c.u;
  c.h = (__bf16)b.z; r[6] = c.u; c.h = (__bf16)b.w; r[7] = c.u;
  return r;
}

__device__ __forceinline__ void async_copy16(const void* g, void* l) {
  __builtin_amdgcn_global_load_lds(
      (const __attribute__((address_space(1))) void*)g,
      (__attribute__((address_space(3))) void*)l, 16, 0, 0);
}

// Compiler-proof prefetch load: volatile asm keeps issue position/order.
__device__ __forceinline__ float4 gldx4(const float* p) {
  float4 r;
  asm volatile("global_load_dwordx4 %0, %1, off" : "=v"(r) : "v"(p));
  return r;
}

__device__ __forceinline__ void cast8(const float* __restrict__ src,
                                      unsigned short* __restrict__ dst, size_t i) {
  float4 v0 = *(const float4*)(src + i);
  float4 v1 = *(const float4*)(src + i + 4);
  ushort4 h0, h1;
  h0.x = f2bf(v0.x); h0.y = f2bf(v0.y); h0.z = f2bf(v0.z); h0.w = f2bf(v0.w);
  h1.x = f2bf(v1.x); h1.y = f2bf(v1.y); h1.z = f2bf(v1.z); h1.w = f2bf(v1.w);
  *(ushort4*)(dst + i)     = h0;
  *(ushort4*)(dst + i + 4) = h1;
}

// ---------------------------------------------------------------------------
// Stage one [ROWS x 64] bf16 tile into LDS via global_load_lds width=16,
// fetch-side XOR swizzle (chunk' = chunk ^ (row&7)) -> conflict-free b128.
// ---------------------------------------------------------------------------
template<int ROWS>
__device__ __forceinline__ void stage_tile(
    const unsigned short* __restrict__ base, size_t row0, int stride, int kofs,
    unsigned short* Ls, int tid) {
  constexpr int IT = ROWS / 32;           // 16B chunks per thread
  const int wave = tid >> 6, lane = tid & 63;
#pragma unroll
  for (int j = 0; j < IT; ++j) {
    int s   = wave * (IT * 64) + j * 64 + lane;   // linear 16B slot
    int row = s >> 3;
    int kc  = (s & 7) ^ (row & 7);                // fetch-side swizzle
    const unsigned short* g = base + (row0 + (size_t)row) * (size_t)stride + kofs + kc * 8;
    async_copy16(g, (char*)Ls + wave * (IT * 1024) + j * 1024);
  }
}

// ---------------------------------------------------------------------------
// Core: C[MF*32 x 128] = A[MF*32 x K] @ B[128 x K]^T (bf16, K-contig) via
// mfma_f32_16x16x32_bf16, 4 waves 2x2. Ends with __syncthreads().
// (Used by small GEMMs: ffn12, gemm3p.)
// ---------------------------------------------------------------------------
template<int KLEN, int MF>
__device__ __forceinline__ void mfma_tile_nt(
    const unsigned short* __restrict__ Abf, size_t a_row0, int astride,
    const unsigned short* __restrict__ Bbf, size_t b_row0, int bstride, int k0,
    unsigned short* As, unsigned short* Bs, f32x4 (&acc)[MF][4]) {
  const int tid  = threadIdx.x;
  const int lane = tid & 63;
  const int wave = tid >> 6;
  const int m0 = (wave >> 1) * (MF * 16), n0 = (wave & 1) * 64;

  for (int kk = 0; kk < KLEN; kk += 64) {
    stage_tile<MF * 32>(Abf, a_row0, astride, k0 + kk, As, tid);
    stage_tile<128>(Bbf, b_row0, bstride, k0 + kk, Bs, tid);
    __syncthreads();
#pragma unroll
    for (int ks = 0; ks < 2; ++ks) {
      int cbase = ks * 4 + (lane >> 4);
      int koff  = (cbase ^ (lane & 7)) * 8;   // row&7 == lane&7 for all frags
      bf16x8 a[MF], b[4];
#pragma unroll
      for (int mf = 0; mf < MF; ++mf)
        a[mf] = *(const bf16x8*)(As + (m0 + mf * 16 + (lane & 15)) * 64 + koff);
#pragma unroll
      for (int nf = 0; nf < 4; ++nf)
        b[nf] = *(const bf16x8*)(Bs + (n0 + nf * 16 + (lane & 15)) * 64 + koff);
#pragma unroll
      for (int mf = 0; mf < MF; ++mf)
#pragma unroll
        for (int nf = 0; nf < 4; ++nf)
          acc[mf][nf] = __builtin_amdgcn_mfma_f32_16x16x32_bf16(
              a[mf], b[nf], acc[mf][nf], 0, 0, 0);
    }
    __syncthreads();
  }
}

// ---------------------------------------------------------------------------
// Pipelined core, compiler-proof (asm loads + sched_barrier pinning).
// Per K-step: [issue A(t+1) gload_lds + B(t+1) asm loads] | SB(0) |
// [setprio(1) MFMA cluster setprio(0)] | SB(0) | [vmcnt(0); cvt+ds_write B]
// | barrier. Issue-to-wait distance = full compute phase -> covers L2/L3
// latency of gen_w2 (L3-resident).
// LDS: As = 2 * MF*32*64 shorts, Bs = 2 * 128*64 shorts (64 KB total @MF=4).
// ---------------------------------------------------------------------------
template<int KLEN, int MF>
__device__ __forceinline__ void mfma_pipe_bf32(
    const unsigned short* __restrict__ Abf, size_t a_row0, int astride,
    const float* __restrict__ Bf, size_t b_row0, int bstride,
    unsigned short* As, unsigned short* Bs, f32x4 (&acc)[MF][4]) {
  const int tid  = threadIdx.x;
  const int lane = tid & 63;
  const int wave = tid >> 6;
  const int m0 = (wave >> 1) * (MF * 16), n0 = (wave & 1) * 64;
  constexpr int ABUF = MF * 32 * 64;   // shorts per A buffer
  constexpr int BBUF = 128 * 64;       // shorts per B buffer
  constexpr int NT   = KLEN / 64;

  float4 v[8];  // in-flight B f32 regs (statically indexed only)

  auto loadB = [&](int kk) {
#pragma unroll
    for (int jj = 0; jj < 4; ++jj) {
      int s   = wave * 256 + jj * 64 + lane;   // linear 16B slot
      int row = s >> 3;
      int kc  = (s & 7) ^ (row & 7);           // fetch-side swizzle
      const float* g = Bf + (b_row0 + (size_t)row) * (size_t)bstride + kk + kc * 8;
      v[2 * jj]     = gldx4(g);
      v[2 * jj + 1] = gldx4(g + 4);
    }
  };
  auto writeB = [&](unsigned short* Bd) {
#pragma unroll
    for (int jj = 0; jj < 4; ++jj) {
      int s = wave * 256 + jj * 64 + lane;
      *(u16x8*)(Bd + s * 8) = cvt8_hw(v[2 * jj], v[2 * jj + 1]);  // one b128 store
    }
  };
  auto compute = [&](const unsigned short* Ab, const unsigned short* Bb) {
    __builtin_amdgcn_s_setprio(1);
#pragma unroll
    for (int ks = 0; ks < 2; ++ks) {
      int cbase = ks * 4 + (lane >> 4);
      int koff  = (cbase ^ (lane & 7)) * 8;
      bf16x8 a[MF], b[4];
#pragma unroll
      for (int mf = 0; mf < MF; ++mf)
        a[mf] = *(const bf16x8*)(Ab + (m0 + mf * 16 + (lane & 15)) * 64 + koff);
#pragma unroll
      for (int nf = 0; nf < 4; ++nf)
        b[nf] = *(const bf16x8*)(Bb + (n0 + nf * 16 + (lane & 15)) * 64 + koff);
#pragma unroll
      for (int mf = 0; mf < MF; ++mf)
#pragma unroll
        for (int nf = 0; nf < 4; ++nf)
          acc[mf][nf] = __builtin_amdgcn_mfma_f32_16x16x32_bf16(
              a[mf], b[nf], acc[mf][nf], 0, 0, 0);
    }
    __builtin_amdgcn_s_setprio(0);
  };

  // prologue: stage tile 0 (not hideable, once)
  stage_tile<MF * 32>(Abf, a_row0, astride, 0, As, tid);
  loadB(0);
  asm volatile("s_waitcnt vmcnt(0)" ::: "memory");
  __builtin_amdgcn_sched_barrier(0);
  writeB(Bs);
  __syncthreads();

  int cur = 0;
  for (int t = 0; t < NT - 1; ++t) {
    // issue next tile's loads FIRST (A: async->LDS; B: asm -> regs)
    stage_tile<MF * 32>(Abf, a_row0, astride, (t + 1) * 64, As + (cur ^ 1) * ABUF, tid);
    loadB((t + 1) * 64);
    __builtin_amdgcn_sched_barrier(0);   // pin: loads stay issued up here
    // compute current tile while loads fly (~500 cyc window)
    compute(As + cur * ABUF, Bs + cur * BBUF);
    __builtin_amdgcn_sched_barrier(0);   // pin: wait happens after compute
    asm volatile("s_waitcnt vmcnt(0)" ::: "memory");  // B(t+1) + A(t+1) landed
    __builtin_amdgcn_sched_barrier(0);
    writeB(Bs + (cur ^ 1) * BBUF);
    __syncthreads();                     // B writes visible; A staged
    cur ^= 1;
  }
  compute(As + cur * ABUF, Bs + cur * BBUF);
  __syncthreads();     // LDS is reused by caller epilogues
}

template<int MF>
__device__ __forceinline__ void zero_accN(f32x4 (&acc)[MF][4]) {
#pragma unroll
  for (int i = 0; i < MF; ++i)
#pragma unroll
    for (int j = 0; j < 4; ++j) {
      f32x4 z = {0.f, 0.f, 0.f, 0.f};
      acc[i][j] = z;
    }
}

// ---------------------------------------------------------------------------
// prep: hg = silu(m_tok @ gen_w1^T + gen_b1) -> bf16; x -> bf16;
// also casts W1/W2/W3 to bf16 (folded to save launches).
// ---------------------------------------------------------------------------
__global__ __launch_bounds__(256) void prep_kernel(
    const float* __restrict__ x, const float* __restrict__ m_tok,
    const float* __restrict__ gen_w1, const float* __restrict__ gen_b1,
    const float* __restrict__ W1, const float* __restrict__ W2,
    const float* __restrict__ W3,
    unsigned short* __restrict__ xb, unsigned short* __restrict__ hgb,
    unsigned short* __restrict__ W1b, unsigned short* __restrict__ W2b,
    unsigned short* __restrict__ W3b) {
  __shared__ float mt[4 * DM];
  const int tid = threadIdx.x;
  const size_t t0 = (size_t)blockIdx.x * 4;
#pragma unroll
  for (int k = 0; k < 4; ++k) mt[k * 256 + tid] = m_tok[t0 * DM + k * 256 + tid];
#pragma unroll
  for (int k = 0; k < 8; ++k) {
    size_t idx = t0 * DIMX + k * 256 + tid;
    xb[idx] = f2bf(x[idx]);
  }
  // folded weight casts: 1,048,576 elems each = 2 chunks/thread each
  {
    size_t base = ((size_t)blockIdx.x * 256 + tid) * 8;
#pragma unroll
    for (int it = 0; it < 2; ++it) {
      size_t idx = base + (size_t)it * 524288;
      cast8(W1, W1b, idx);
      cast8(W2, W2b, idx);
      cast8(W3, W3b, idx);
    }
  }
  __syncthreads();
#pragma unroll
  for (int hh = 0; hh < 2; ++hh) {
    int h = hh * 256 + tid;
    float a0, a1, a2, a3;
    a0 = a1 = a2 = a3 = gen_b1[h];
    const float* wr = gen_w1 + (size_t)h * DM;
    for (int d = 0; d < DM; d += 4) {
      float4 w = *(const float4*)(wr + d);
      a0 += w.x * mt[d]       + w.y * mt[d + 1]       + w.z * mt[d + 2]       + w.w * mt[d + 3];
      a1 += w.x * mt[256 + d] + w.y * mt[256 + d + 1] + w.z * mt[256 + d + 2] + w.w * mt[256 + d + 3];
      a2 += w.x * mt[512 + d] + w.y * mt[512 + d + 1] + w.z * mt[512 + d + 2] + w.w * mt[512 + d + 3];
      a3 += w.x * mt[768 + d] + w.y * mt[768 + d + 1] + w.z * mt[768 + d + 2] + w.w * mt[768 + d + 3];
    }
    hgb[(t0 + 0) * GENH + h] = f2bf(silu_f(a0));
    hgb[(t0 + 1) * GENH + h] = f2bf(silu_f(a1));
    hgb[(t0 + 2) * GENH + h] = f2bf(silu_f(a2));
    hgb[(t0 + 3) * GENH + h] = f2bf(silu_f(a3));
  }
}

// ---------------------------------------------------------------------------
// ffn12 body: fused x@W1^T / x@W2^T + bias + silu-mul -> hb (bf16).
// Tile 32 tok x 128 o, 512 blocks. Waves 2x2 (16x64 each).
// ---------------------------------------------------------------------------
__device__ __forceinline__ void ffn12_body(
    int bx, const unsigned short* __restrict__ xb, const unsigned short* __restrict__ W1b,
    const unsigned short* __restrict__ W2b, const float* __restrict__ pb1,
    const float* __restrict__ pb2, unsigned short* __restrict__ hb,
    unsigned short* As, unsigned short* B1s, unsigned short* B2s) {
  const int tid = threadIdx.x, lane = tid & 63, wave = tid >> 6;
  const int ob = bx & 15, tb = bx >> 4;
  const size_t t0 = (size_t)tb * 32, o0 = (size_t)ob * 128;
  const int m0 = (wave >> 1) * 16, n0 = (wave & 1) * 64;

  f32x4 acc1[4], acc2[4];
#pragma unroll
  for (int j = 0; j < 4; ++j) {
    f32x4 z = {0.f, 0.f, 0.f, 0.f};
    acc1[j] = z; acc2[j] = z;
  }

  for (int kk = 0; kk < DIMX; kk += 64) {
    stage_tile<32>(xb, t0, DIMX, kk, As, tid);
    stage_tile<128>(W1b, o0, DIMX, kk, B1s, tid);
    stage_tile<128>(W2b, o0, DIMX, kk, B2s, tid);
    __syncthreads();
#pragma unroll
    for (int ks = 0; ks < 2; ++ks) {
      int cbase = ks * 4 + (lane >> 4);
      int koff  = (cbase ^ (lane & 7)) * 8;
      bf16x8 a, b1[4], b2[4];
      a = *(const bf16x8*)(As + (m0 + (lane & 15)) * 64 + koff);
#pragma unroll
      for (int nf = 0; nf < 4; ++nf) {
        b1[nf] = *(const bf16x8*)(B1s + (n0 + nf * 16 + (lane & 15)) * 64 + koff);
        b2[nf] = *(const bf16x8*)(B2s + (n0 + nf * 16 + (lane & 15)) * 64 + koff);
      }
#pragma unroll
      for (int nf = 0; nf < 4; ++nf) {
        acc1[nf] = __builtin_amdgcn_mfma_f32_16x16x32_bf16(a, b1[nf], acc1[nf], 0, 0, 0);
        acc2[nf] = __builtin_amdgcn_mfma_f32_16x16x32_bf16(a, b2[nf], acc2[nf], 0, 0, 0);
      }
    }
    __syncthreads();
  }

  const int q = lane >> 4;
  float b1v[4], b2v[4];
#pragma unroll
  for (int nf = 0; nf < 4; ++nf) {
    b1v[nf] = pb1[o0 + n0 + nf * 16 + (lane & 15)];
    b2v[nf] = pb2[o0 + n0 + nf * 16 + (lane & 15)];
  }
#pragma unroll
  for (int nf = 0; nf < 4; ++nf)
#pragma unroll
    for (int rg = 0; rg < 4; ++rg) {
      size_t trow = t0 + m0 + q * 4 + rg;
      size_t col  = o0 + n0 + nf * 16 + (lane & 15);
      float v1 = acc1[nf][rg] + b1v[nf];
      float v2 = acc2[nf][rg] + b2v[nf];
      hb[trow * HID + col] = f2bf(silu_f(v1) * v2);
    }
}

// ---------------------------------------------------------------------------
// memuv body: fused paths 1&2, B read directly from f32 gen_w2 via the
// pipelined core. Block = [128 tok x 128 o] tile; epilogue contracts vs x
// staged in LDS [128x128] bf16 with address swizzle; leaders store float4
// partials. Strip-consecutive XCD map preserved.
// ---------------------------------------------------------------------------
union SmemUV {
  struct { unsigned short As[2 * 128 * 64], Bs[2 * 128 * 64]; } ab;  // 64 KB
  struct { unsigned short Xs[128 * 128]; } ep;                       // 32 KB
};

__device__ __forceinline__ void memuv_body(
    int bx, const unsigned short* __restrict__ hgb, const float* __restrict__ gw2,
    const float* __restrict__ gen_b2, const unsigned short* __restrict__ xb,
    float* __restrict__ up, SmemUV& sm) {
  const int s8 = bx & 7, w = bx >> 3;
  const int tb = w & 7, strip = (w >> 3) * 8 + s8;   // 0..511
  const size_t o0 = (size_t)strip * 128, t0 = (size_t)tb * 128;
  const int j  = strip >> 2;        // u column (0..127)
  const int d0 = (strip & 3) * 128; // d-range within the r row

  f32x4 acc[4][4];
  zero_accN<4>(acc);
  mfma_pipe_bf32<GENH, 4>(hgb, t0, GENH, gw2, o0, GENH, sm.ab.As, sm.ab.Bs, acc);

  const int tid = threadIdx.x, lane = tid & 63, wave = tid >> 6;
  // stage x tile [128 t x 128 d] bf16 with chunk swizzle ^(((row>>2)&3)<<1)
#pragma unroll
  for (int i = 0; i < 8; ++i) {
    int qq = i * 256 + tid;         // 8-short chunks, 2048 total
    int row = qq >> 4, c = qq & 15;
    const unsigned short* src = xb + (t0 + (size_t)row) * DIMX + d0 + c * 8;
    ushort4 v0 = *(const ushort4*)src;
    ushort4 v1 = *(const ushort4*)(src + 4);
    int cs = c ^ (((row >> 2) & 3) << 1);
    unsigned short* dst = sm.ep.Xs + row * 128 + cs * 8;
    *(ushort4*)dst = v0;
    *(ushort4*)(dst + 4) = v1;
  }
  __syncthreads();

  const int m0 = (wave >> 1) * 64, n0 = (wave & 1) * 64;
  const int q = lane >> 4, l15 = lane & 15;
  float gbv[4];
#pragma unroll
  for (int i = 0; i < 4; ++i)
    gbv[i] = gen_b2[o0 + n0 + i * 16 + l15];

  const int p = (strip & 3) * 2 + (wave & 1);
  float* upd = up + (size_t)p * (128 * 1024) + (size_t)j * 1024 + t0;
#pragma unroll
  for (int mf = 0; mf < 4; ++mf) {
    f32x4 vals;
#pragma unroll
    for (int rg = 0; rg < 4; ++rg) {
      int trow = m0 + mf * 16 + q * 4 + rg;
      int swz  = ((trow >> 2) & 3) << 1;
      float val = 0.f;
#pragma unroll
      for (int nf = 0; nf < 4; ++nf) {
        int col = n0 + nf * 16 + l15;
        int idx = trow * 128 + (((col >> 3) ^ swz) << 3) + (col & 7);
        val += (acc[mf][nf][rg] + gbv[nf]) * bf2f(sm.ep.Xs[idx]);
      }
      val += __shfl_xor(val, 1);
      val += __shfl_xor(val, 2);
      val += __shfl_xor(val, 4);
      val += __shfl_xor(val, 8);
      vals[rg] = val;
    }
    if (l15 == 0)
      *(f32x4*)(upd + m0 + mf * 16 + q * 4) = vals;
  }
}

// K2 = {ffn12 (512 blocks)} ++ {memuv (4096 blocks)}: independent work,
// ffn12 hides under memuv. 512 % 8 == 0 keeps memuv's XCD strip map intact.
union SmemK2 {
  struct { unsigned short As[32 * 64], B1s[128 * 64], B2s[128 * 64]; } f; // 36 KB
  SmemUV m;                                                              // 64 KB
};

__global__ __launch_bounds__(256, 2) void k2_kernel(
    const unsigned short* __restrict__ xb, const unsigned short* __restrict__ W1b,
    const unsigned short* __restrict__ W2b, const float* __restrict__ b1,
    const float* __restrict__ b2, unsigned short* __restrict__ hb,
    const unsigned short* __restrict__ hgb, const float* __restrict__ gw2,
    const float* __restrict__ gen_b2, float* __restrict__ up) {
  __shared__ SmemK2 sm;
  const int bx = blockIdx.x;
  if (bx < 512)
    ffn12_body(bx, xb, W1b, W2b, b1, b2, hb, sm.f.As, sm.f.B1s, sm.f.B2s);
  else
    memuv_body(bx - 512, hgb, gw2, gen_b2, xb, up, sm.m);
}

// ---------------------------------------------------------------------------
// gemm3p body: yp[slice] = hb @ W3b^T (partial K), 64x128 tiles.
// 256 blocks: 16 t-tiles x 4 o-tiles x 4 K-slices (KTILE=512).
// ---------------------------------------------------------------------------
__device__ __forceinline__ void gemm3p_body(
    int bx, const unsigned short* __restrict__ hb, const unsigned short* __restrict__ W3b,
    float* __restrict__ yp, unsigned short* As, unsigned short* Bs) {
  const int slice = bx >> 6, r6 = bx & 63;
  const int ob = r6 & 3, tb = r6 >> 2;
  const size_t o0 = (size_t)ob * 128, t0 = (size_t)tb * 64;
  const int k0 = slice * 512;
  f32x4 acc[2][4];
  zero_accN<2>(acc);
  mfma_tile_nt<512, 2>(hb, t0, HID, W3b, o0, HID, k0, As, Bs, acc);

  const int tid = threadIdx.x, lane = tid & 63, wave = tid >> 6;
  const int m0 = (wave >> 1) * 32, n0 = (wave & 1) * 64;
  float* out = yp + (size_t)slice * (TOK * DIMX);
#pragma unroll
  for (int nf = 0; nf < 4; ++nf) {
    int n = n0 + nf * 16 + (lane & 15);
#pragma unroll
    for (int mf = 0; mf < 2; ++mf) {
      int mb = m0 + mf * 16 + ((lane >> 4) << 2);
#pragma unroll
      for (int rg = 0; rg < 4; ++rg)
        out[(t0 + mb + rg) * DIMX + o0 + n] = acc[mf][nf][rg];
    }
  }
}

// ---------------------------------------------------------------------------
// hmem body: u = sum of 8 partials (coalesced in t); h_mem = silu(u1)*u2.
// ---------------------------------------------------------------------------
__device__ __forceinline__ void hmem_body(int bx, const float* __restrict__ up,
                                          float* __restrict__ hm) {
  int i = bx * 256 + threadIdx.x;          // 65536
  int t = i & 1023, r = i >> 10;           // r in 0..63
  float u1 = 0.f, u2 = 0.f;
#pragma unroll
  for (int p = 0; p < 8; ++p) {
    u1 += up[(size_t)p * (128 * 1024) + (size_t)r * 1024 + t];
    u2 += up[(size_t)p * (128 * 1024) + (size_t)(64 + r) * 1024 + t];
  }
  hm[(size_t)t * RR + r] = silu_f(u1) * u2;
}

// K3 = {gemm3p (256 blocks)} ++ {hmem (256 blocks)}: independent work.
union SmemK3 {
  struct { unsigned short As[64 * 64], Bs[128 * 64]; } g;  // 24 KB
};

__global__ __launch_bounds__(256) void k3_kernel(
    const unsigned short* __restrict__ hb, const unsigned short* __restrict__ W3b,
    float* __restrict__ yp, const float* __restrict__ up, float* __restrict__ hm) {
  __shared__ SmemK3 sm;
  const int bx = blockIdx.x;
  if (bx < 256)
    gemm3p_body(bx, hb, W3b, yp, sm.g.As, sm.g.Bs);
  else
    hmem_body(bx - 256, up, hm);
}

// ---------------------------------------------------------------------------
// memy: fused path 3, B read directly from f32 gen_w2 via pipelined core.
// Epilogue contracts vs h_mem in LDS [128x64] f32 with chunk swizzle;
// single-writer y = (b3 + sum4 yp) + g*val (yreduce folded in).
// ---------------------------------------------------------------------------
union SmemY {
  struct { unsigned short As[2 * 128 * 64], Bs[2 * 128 * 64]; } ab;  // 64 KB
  struct { float Hs[128 * 64]; } ep;                                 // 32 KB
};

__global__ __launch_bounds__(256, 2) void memy_kernel(
    const unsigned short* __restrict__ hgb, const float* __restrict__ gw2,
    const float* __restrict__ gen_b2, const float* __restrict__ hmem,
    const float* __restrict__ yp, const float* __restrict__ b3,
    const float* __restrict__ mem_gate, float* __restrict__ y) {
  __shared__ SmemY sm;
  const int bx = blockIdx.x;
  const int s8 = bx & 7, w = bx >> 3;
  const int tb = w & 7, strip = (w >> 3) * 8 + s8;   // 0..255
  const size_t brow0 = (size_t)O3BASE + (size_t)strip * 128;
  const size_t t0 = (size_t)tb * 128;

  f32x4 acc[4][4];
  zero_accN<4>(acc);
  mfma_pipe_bf32<GENH, 4>(hgb, t0, GENH, gw2, brow0, GENH, sm.ab.As, sm.ab.Bs, acc);

  const int tid = threadIdx.x, lane = tid & 63, wave = tid >> 6;
  // stage h_mem tile [128 t x 64 r] f32, chunk swizzle ^(((row>>2)&3)<<2)
#pragma unroll
  for (int i = 0; i < 8; ++i) {
    int qq = i * 256 + tid;         // float4 chunks, 2048 total
    int row = qq >> 4, c = qq & 15;
    float4 v = *(const float4*)(hmem + (t0 + (size_t)row) * RR + c * 4);
    int cs = c ^ (((row >> 2) & 3) << 2);
    *(float4*)(sm.ep.Hs + row * 64 + cs * 4) = v;
  }
  __syncthreads();

  const int m0 = (wave >> 1) * 64, n0 = (wave & 1) * 64;
  const int q = lane >> 4, l15 = lane & 15;
  const float g = 1.f / (1.f + __expf(-mem_gate[0]));
  float gbv[4];
#pragma unroll
  for (int i = 0; i < 4; ++i)
    gbv[i] = gen_b2[brow0 + n0 + i * 16 + l15];

  const int d = strip * 2 + (wave & 1);
  const float b3v = b3[d];
#pragma unroll
  for (int mf = 0; mf < 4; ++mf)
#pragma unroll
    for (int rg = 0; rg < 4; ++rg) {
      int trow = m0 + mf * 16 + q * 4 + rg;
      int swz  = ((trow >> 2) & 3) << 2;
      float val = 0.f;
#pragma unroll
      for (int nf = 0; nf < 4; ++nf) {
        int r = nf * 16 + l15;
        int idx = trow * 64 + (((r >> 2) ^ swz) << 2) + (r & 3);
        val += (acc[mf][nf][rg] + gbv[nf]) * sm.ep.Hs[idx];
      }
      val += __shfl_xor(val, 1);
      val += __shfl_xor(val, 2);
      val += __shfl_xor(val, 4);
      val += __shfl_xor(val, 8);
      if (l15 == 0) {
        size_t gi = (t0 + trow) * DIMX + d;
        float base = b3v + yp[gi]
                   + yp[(size_t)1 * (TOK * DIMX) + gi]
                   + yp[(size_t)2 * (TOK * DIMX) + gi]
                   + yp[(size_t)3 * (TOK * DIMX) + gi];
        y[gi] = base + g * val;
      }
    }
}

// ---------------------------------------------------------------------------
extern "C" void kernel_launch(void* const* d_in, const int* in_sizes, int n_in,
                              void* d_out, int out_size, void* d_ws, size_t ws_size,
                              hipStream_t stream) {
  const float* x        = (const float*)d_in[0];
  const float* m_tok    = (const float*)d_in[1];
  const float* W1       = (const float*)d_in[2];
  const float* W2       = (const float*)d_in[3];
  const float* W3       = (const float*)d_in[4];
  const float* b1       = (const float*)d_in[5];
  const float* b2       = (const float*)d_in[6];
  const float* b3       = (const float*)d_in[7];
  const float* gen_w1   = (const float*)d_in[8];
  const float* gen_b1   = (const float*)d_in[9];
  const float* gen_w2   = (const float*)d_in[10];
  const float* gen_b2   = (const float*)d_in[11];
  const float* mem_gate = (const float*)d_in[12];
  float* y = (float*)d_out;

  char* ws = (char*)d_ws;
#define KB(v) ((size_t)(v) << 10)
  unsigned short* xb  = (unsigned short*)(ws);               // 1 MB
  unsigned short* hgb = (unsigned short*)(ws + KB(1024));    // 1 MB
  unsigned short* hb  = (unsigned short*)(ws + KB(2048));    // 4 MB
  float* up  = (float*)(ws + KB(6144));                      // 4 MB
  float* hm  = (float*)(ws + KB(10240));                     // 512 KB
  float* yp  = (float*)(ws + KB(10752));                     // 8 MB (4 slices)
  unsigned short* W1b = (unsigned short*)(ws + KB(21248));   // 2 MB
  unsigned short* W2b = (unsigned short*)(ws + KB(23296));   // 2 MB
  unsigned short* W3b = (unsigned short*)(ws + KB(25344));   // 2 MB
#undef KB

  // K1: casts + hypernet layer-1
  prep_kernel<<<256, 256, 0, stream>>>(x, m_tok, gen_w1, gen_b1, W1, W2, W3,
                                       xb, hgb, W1b, W2b, W3b);
  // K2: base-FFN up-proj (hidden under) memory-path u/v GEMM (pinned pipeline)
  k2_kernel<<<512 + 4096, 256, 0, stream>>>(xb, W1b, W2b, b1, b2, hb,
                                            hgb, gen_w2, gen_b2, up);
  // K3: base-FFN down-proj partials (hidden over) h_mem reduction
  k3_kernel<<<256 + 256, 256, 0, stream>>>(hb, W3b, yp, up, hm);
  // K4: path-3 GEMM + epilogue, yreduce folded into the single-writer store
  memy_kernel<<<2048, 256, 0, stream>>>(hgb, gen_w2, gen_b2, hm, yp, b3,
                                        mem_gate, y);
}

// Round 5
// 473.365 us; speedup vs baseline: 1.1449x; 1.0431x over previous
//
#include <hip/hip_runtime.h>
#include <cstdint>
#include <cstddef>

// Problem dims (fixed)
#define TOK   1024   // B*T
#define DIMX  512
#define HID   2048
#define DM    256
#define GENH  512
#define RR    64
#define O3BASE 65536 // start row of path-3 block in gen_w2 (2*R*DIM)

typedef __bf16 bf16x8 __attribute__((ext_vector_type(8)));
typedef float  f32x4  __attribute__((ext_vector_type(4)));
typedef unsigned short u16x8 __attribute__((ext_vector_type(8)));

#define SB0 __builtin_amdgcn_sched_barrier(0)
#define BAR __builtin_amdgcn_s_barrier()

__device__ __forceinline__ unsigned short f2bf(float f) {
  union { float f; uint32_t u; } v; v.f = f;
  return (unsigned short)((v.u + 0x7fffu + ((v.u >> 16) & 1u)) >> 16);
}
__device__ __forceinline__ float bf2f(unsigned short h) {
  union { uint32_t u; float f; } v; v.u = (uint32_t)h << 16;
  return v.f;
}
__device__ __forceinline__ float silu_f(float x) { return x / (1.f + __expf(-x)); }

// HW f32->bf16 (RNE; lowers to v_cvt_pk_bf16_f32 pairs on gfx950)
__device__ __forceinline__ u16x8 cvt8_hw(float4 a, float4 b) {
  union { __bf16 h; unsigned short u; } c;
  u16x8 r;
  c.h = (__bf16)a.x; r[0] = c.u; c.h = (__bf16)a.y; r[1] = c.u;
  c.h = (__bf16)a.z; r[2] = c.u; c.h = (__bf16)a.w; r[3] = c.u;
  c.h = (__bf16)b.x; r[4] = c.u; c.h = (__bf16)b.y; r[5] = c.u;
  c.h = (__bf16)b.z; r[6] = c.u; c.h = (__bf16)b.w; r[7] = c.u;
  return r;
}

__device__ __forceinline__ void async_copy16(const void* g, void* l) {
  __builtin_amdgcn_global_load_lds(
      (const __attribute__((address_space(1))) void*)g,
      (__attribute__((address_space(3))) void*)l, 16, 0, 0);
}

// Compiler-proof prefetch load: volatile asm keeps issue position/order.
__device__ __forceinline__ float4 gldx4(const float* p) {
  float4 r;
  asm volatile("global_load_dwordx4 %0, %1, off" : "=v"(r) : "v"(p));
  return r;
}

__device__ __forceinline__ void cast8(const float* __restrict__ src,
                                      unsigned short* __restrict__ dst, size_t i) {
  float4 v0 = *(const float4*)(src + i);
  float4 v1 = *(const float4*)(src + i + 4);
  ushort4 h0, h1;
  h0.x = f2bf(v0.x); h0.y = f2bf(v0.y); h0.z = f2bf(v0.z); h0.w = f2bf(v0.w);
  h1.x = f2bf(v1.x); h1.y = f2bf(v1.y); h1.z = f2bf(v1.z); h1.w = f2bf(v1.w);
  *(ushort4*)(dst + i)     = h0;
  *(ushort4*)(dst + i + 4) = h1;
}

// ---------------------------------------------------------------------------
// Stage one [ROWS x 64] bf16 tile into LDS via global_load_lds width=16,
// fetch-side XOR swizzle (chunk' = chunk ^ (row&7)) -> conflict-free b128.
// 256-thread (4-wave) version for ffn12/gemm3p.
// ---------------------------------------------------------------------------
template<int ROWS>
__device__ __forceinline__ void stage_tile(
    const unsigned short* __restrict__ base, size_t row0, int stride, int kofs,
    unsigned short* Ls, int tid) {
  constexpr int IT = ROWS / 32;           // 16B chunks per thread
  const int wave = tid >> 6, lane = tid & 63;
#pragma unroll
  for (int j = 0; j < IT; ++j) {
    int s   = wave * (IT * 64) + j * 64 + lane;   // linear 16B slot
    int row = s >> 3;
    int kc  = (s & 7) ^ (row & 7);                // fetch-side swizzle
    const unsigned short* g = base + (row0 + (size_t)row) * (size_t)stride + kofs + kc * 8;
    async_copy16(g, (char*)Ls + wave * (IT * 1024) + j * 1024);
  }
}

// ---------------------------------------------------------------------------
// Small-GEMM core (ffn12/gemm3p): C[MF*32 x 128] = A @ B^T, 4 waves 2x2.
// ---------------------------------------------------------------------------
template<int KLEN, int MF>
__device__ __forceinline__ void mfma_tile_nt(
    const unsigned short* __restrict__ Abf, size_t a_row0, int astride,
    const unsigned short* __restrict__ Bbf, size_t b_row0, int bstride, int k0,
    unsigned short* As, unsigned short* Bs, f32x4 (&acc)[MF][4], int tid) {
  const int lane = tid & 63;
  const int wave = tid >> 6;
  const int m0 = (wave >> 1) * (MF * 16), n0 = (wave & 1) * 64;

  for (int kk = 0; kk < KLEN; kk += 64) {
    stage_tile<MF * 32>(Abf, a_row0, astride, k0 + kk, As, tid);
    stage_tile<128>(Bbf, b_row0, bstride, k0 + kk, Bs, tid);
    __syncthreads();
#pragma unroll
    for (int ks = 0; ks < 2; ++ks) {
      int cbase = ks * 4 + (lane >> 4);
      int koff  = (cbase ^ (lane & 7)) * 8;   // row&7 == lane&7 for all frags
      bf16x8 a[MF], b[4];
#pragma unroll
      for (int mf = 0; mf < MF; ++mf)
        a[mf] = *(const bf16x8*)(As + (m0 + mf * 16 + (lane & 15)) * 64 + koff);
#pragma unroll
      for (int nf = 0; nf < 4; ++nf)
        b[nf] = *(const bf16x8*)(Bs + (n0 + nf * 16 + (lane & 15)) * 64 + koff);
#pragma unroll
      for (int mf = 0; mf < MF; ++mf)
#pragma unroll
        for (int nf = 0; nf < 4; ++nf)
          acc[mf][nf] = __builtin_amdgcn_mfma_f32_16x16x32_bf16(
              a[mf], b[nf], acc[mf][nf], 0, 0, 0);
    }
    __syncthreads();
  }
}

template<int MF>
__device__ __forceinline__ void zero_accN(f32x4 (&acc)[MF][4]) {
#pragma unroll
  for (int i = 0; i < MF; ++i)
#pragma unroll
    for (int j = 0; j < 4; ++j) {
      f32x4 z = {0.f, 0.f, 0.f, 0.f};
      acc[i][j] = z;
    }
}

// ---------------------------------------------------------------------------
// 256x256x512 8-phase GEMM core (8 waves / 512 thr, 2M x 4N wave grid).
// A = bf16 [256 x 64] via global_load_lds (fetch-side swizzle, linear dest);
// B = f32 source, reg-staged (asm gldx4) -> cvt -> ds_write_b128 (same layout).
// Double-buffered (128 KB). Per K-tile: 4 phases of {ds-read quadrant +
// staged issue | barrier | 16 MFMA (setprio) | barrier}; counted vmcnt(4) at
// phase 3 (B loads stay in flight ~3 phases); vmcnt(0)+lgkmcnt(0) once per
// tile. acc[8][4] per wave covers 128x64 of C.
// ---------------------------------------------------------------------------
__device__ __forceinline__ void mfma_256_8ph(
    const unsigned short* __restrict__ Abf, size_t a_row0,
    const float* __restrict__ Bf, size_t b_row0,
    unsigned short* As, unsigned short* Bs, f32x4 (&acc)[8][4]) {
  const int tid = threadIdx.x, lane = tid & 63, wave = tid >> 6;
  const int wr = wave >> 2, wc = wave & 3;
  const int m0 = wr * 128, n0 = wc * 64;
  const int l15 = lane & 15;
  constexpr int ABUF = 256 * 64;   // shorts
  constexpr int BBUF = 256 * 64;

  float4 v[8];       // in-flight B f32 regs (static indexing only)
  bf16x8 bfr[4];     // B fragments (live across 2 phases)
  bf16x8 afr[4];     // A fragments (per phase)
  const int sbase = wave * 256 + lane;

  auto stageA = [&](int k0, unsigned short* Ad) {
#pragma unroll
    for (int jj = 0; jj < 4; ++jj) {
      int s = sbase + jj * 64;
      int row = s >> 3;
      int kc  = (s & 7) ^ (row & 7);
      const unsigned short* g = Abf + (a_row0 + (size_t)row) * GENH + k0 + kc * 8;
      async_copy16(g, (char*)Ad + (wave * 4 + jj) * 1024);
    }
  };
  auto loadB01 = [&](int k0) {
#pragma unroll
    for (int jj = 0; jj < 2; ++jj) {
      int s = sbase + jj * 64;
      int row = s >> 3;
      int kc  = (s & 7) ^ (row & 7);
      const float* g = Bf + (b_row0 + (size_t)row) * GENH + k0 + kc * 8;
      v[2 * jj]     = gldx4(g);
      v[2 * jj + 1] = gldx4(g + 4);
    }
  };
  auto loadB23 = [&](int k0) {
#pragma unroll
    for (int jj = 2; jj < 4; ++jj) {
      int s = sbase + jj * 64;
      int row = s >> 3;
      int kc  = (s & 7) ^ (row & 7);
      const float* g = Bf + (b_row0 + (size_t)row) * GENH + k0 + kc * 8;
      v[2 * jj]     = gldx4(g);
      v[2 * jj + 1] = gldx4(g + 4);
    }
  };
  auto writeB = [&](unsigned short* Bd) {
#pragma unroll
    for (int jj = 0; jj < 4; ++jj) {
      int s = sbase + jj * 64;
      *(u16x8*)(Bd + s * 8) = cvt8_hw(v[2 * jj], v[2 * jj + 1]);
    }
  };
  auto rdB = [&](const unsigned short* Bb, int ks) {
    int koff = (((ks << 2) + (lane >> 4)) ^ (lane & 7)) << 3;
#pragma unroll
    for (int nf = 0; nf < 4; ++nf)
      bfr[nf] = *(const bf16x8*)(Bb + (n0 + nf * 16 + l15) * 64 + koff);
  };
  auto rdA = [&](const unsigned short* Ab, int ks, int mh) {
    int koff = (((ks << 2) + (lane >> 4)) ^ (lane & 7)) << 3;
#pragma unroll
    for (int i = 0; i < 4; ++i)
      afr[i] = *(const bf16x8*)(Ab + (m0 + (mh * 4 + i) * 16 + l15) * 64 + koff);
  };
  auto mfma16 = [&](int mh) {
    __builtin_amdgcn_s_setprio(1);
#pragma unroll
    for (int i = 0; i < 4; ++i)
#pragma unroll
      for (int nf = 0; nf < 4; ++nf)
        acc[mh * 4 + i][nf] = __builtin_amdgcn_mfma_f32_16x16x32_bf16(
            afr[i], bfr[nf], acc[mh * 4 + i][nf], 0, 0, 0);
    __builtin_amdgcn_s_setprio(0);
  };

  // prologue: tile 0
  stageA(0, As);
  loadB01(0); loadB23(0);
  asm volatile("s_waitcnt vmcnt(0)" ::: "memory");
  SB0;
  writeB(Bs);
  __syncthreads();

  int cur = 0;
#pragma unroll 1
  for (int t = 0; t < 8; ++t) {
    unsigned short* Ac = As + cur * ABUF;
    unsigned short* Bc = Bs + cur * BBUF;
    unsigned short* An = As + (cur ^ 1) * ABUF;
    unsigned short* Bn = Bs + (cur ^ 1) * BBUF;
    const bool pf = (t < 7);
    const int k1 = (t + 1) * 64;

    // phase 0: ks=0 mh=0; issue B(t+1) loads 0-3
    rdB(Bc, 0); rdA(Ac, 0, 0);
    if (pf) loadB01(k1);
    SB0; BAR; SB0;
    mfma16(0);
    SB0; BAR;

    // phase 1: ks=0 mh=1; issue B(t+1) loads 4-7
    rdA(Ac, 0, 1);
    if (pf) loadB23(k1);
    SB0; BAR; SB0;
    mfma16(1);
    SB0; BAR;

    // phase 2: ks=1 mh=0; issue A(t+1) global_load_lds
    rdB(Bc, 1); rdA(Ac, 1, 0);
    if (pf) stageA(k1, An);
    SB0; BAR; SB0;
    mfma16(0);
    SB0; BAR;

    // phase 3: ks=1 mh=1; counted vmcnt(4) -> B(t+1) landed; cvt+write
    rdA(Ac, 1, 1);
    if (pf) {
      asm volatile("s_waitcnt vmcnt(4)" ::: "memory");
      SB0;
      writeB(Bn);
    }
    SB0; BAR; SB0;
    mfma16(1);
    SB0;
    asm volatile("s_waitcnt vmcnt(0) lgkmcnt(0)" ::: "memory"); // A landed, B writes drained
    BAR;
    cur ^= 1;
  }
}

// ---------------------------------------------------------------------------
// prep: hg = silu(m_tok @ gen_w1^T + gen_b1) -> bf16; x -> bf16;
// also casts W1/W2/W3 to bf16 (folded to save launches).
// ---------------------------------------------------------------------------
__global__ __launch_bounds__(256) void prep_kernel(
    const float* __restrict__ x, const float* __restrict__ m_tok,
    const float* __restrict__ gen_w1, const float* __restrict__ gen_b1,
    const float* __restrict__ W1, const float* __restrict__ W2,
    const float* __restrict__ W3,
    unsigned short* __restrict__ xb, unsigned short* __restrict__ hgb,
    unsigned short* __restrict__ W1b, unsigned short* __restrict__ W2b,
    unsigned short* __restrict__ W3b) {
  __shared__ float mt[4 * DM];
  const int tid = threadIdx.x;
  const size_t t0 = (size_t)blockIdx.x * 4;
#pragma unroll
  for (int k = 0; k < 4; ++k) mt[k * 256 + tid] = m_tok[t0 * DM + k * 256 + tid];
#pragma unroll
  for (int k = 0; k < 8; ++k) {
    size_t idx = t0 * DIMX + k * 256 + tid;
    xb[idx] = f2bf(x[idx]);
  }
  {
    size_t base = ((size_t)blockIdx.x * 256 + tid) * 8;
#pragma unroll
    for (int it = 0; it < 2; ++it) {
      size_t idx = base + (size_t)it * 524288;
      cast8(W1, W1b, idx);
      cast8(W2, W2b, idx);
      cast8(W3, W3b, idx);
    }
  }
  __syncthreads();
#pragma unroll
  for (int hh = 0; hh < 2; ++hh) {
    int h = hh * 256 + tid;
    float a0, a1, a2, a3;
    a0 = a1 = a2 = a3 = gen_b1[h];
    const float* wr = gen_w1 + (size_t)h * DM;
    for (int d = 0; d < DM; d += 4) {
      float4 w = *(const float4*)(wr + d);
      a0 += w.x * mt[d]       + w.y * mt[d + 1]       + w.z * mt[d + 2]       + w.w * mt[d + 3];
      a1 += w.x * mt[256 + d] + w.y * mt[256 + d + 1] + w.z * mt[256 + d + 2] + w.w * mt[256 + d + 3];
      a2 += w.x * mt[512 + d] + w.y * mt[512 + d + 1] + w.z * mt[512 + d + 2] + w.w * mt[512 + d + 3];
      a3 += w.x * mt[768 + d] + w.y * mt[768 + d + 1] + w.z * mt[768 + d + 2] + w.w * mt[768 + d + 3];
    }
    hgb[(t0 + 0) * GENH + h] = f2bf(silu_f(a0));
    hgb[(t0 + 1) * GENH + h] = f2bf(silu_f(a1));
    hgb[(t0 + 2) * GENH + h] = f2bf(silu_f(a2));
    hgb[(t0 + 3) * GENH + h] = f2bf(silu_f(a3));
  }
}

// ---------------------------------------------------------------------------
// ffn12 body (256-thread sub-block): x@W1^T / x@W2^T + bias + silu-mul -> hb.
// ---------------------------------------------------------------------------
__device__ __forceinline__ void ffn12_body(
    int bx, const unsigned short* __restrict__ xb, const unsigned short* __restrict__ W1b,
    const unsigned short* __restrict__ W2b, const float* __restrict__ pb1,
    const float* __restrict__ pb2, unsigned short* __restrict__ hb,
    unsigned short* As, unsigned short* B1s, unsigned short* B2s, int tid) {
  const int lane = tid & 63, wave = tid >> 6;
  const int ob = bx & 15, tb = bx >> 4;
  const size_t t0 = (size_t)tb * 32, o0 = (size_t)ob * 128;
  const int m0 = (wave >> 1) * 16, n0 = (wave & 1) * 64;

  f32x4 acc1[4], acc2[4];
#pragma unroll
  for (int j = 0; j < 4; ++j) {
    f32x4 z = {0.f, 0.f, 0.f, 0.f};
    acc1[j] = z; acc2[j] = z;
  }

  for (int kk = 0; kk < DIMX; kk += 64) {
    stage_tile<32>(xb, t0, DIMX, kk, As, tid);
    stage_tile<128>(W1b, o0, DIMX, kk, B1s, tid);
    stage_tile<128>(W2b, o0, DIMX, kk, B2s, tid);
    __syncthreads();
#pragma unroll
    for (int ks = 0; ks < 2; ++ks) {
      int cbase = ks * 4 + (lane >> 4);
      int koff  = (cbase ^ (lane & 7)) * 8;
      bf16x8 a, b1[4], b2[4];
      a = *(const bf16x8*)(As + (m0 + (lane & 15)) * 64 + koff);
#pragma unroll
      for (int nf = 0; nf < 4; ++nf) {
        b1[nf] = *(const bf16x8*)(B1s + (n0 + nf * 16 + (lane & 15)) * 64 + koff);
        b2[nf] = *(const bf16x8*)(B2s + (n0 + nf * 16 + (lane & 15)) * 64 + koff);
      }
#pragma unroll
      for (int nf = 0; nf < 4; ++nf) {
        acc1[nf] = __builtin_amdgcn_mfma_f32_16x16x32_bf16(a, b1[nf], acc1[nf], 0, 0, 0);
        acc2[nf] = __builtin_amdgcn_mfma_f32_16x16x32_bf16(a, b2[nf], acc2[nf], 0, 0, 0);
      }
    }
    __syncthreads();
  }

  const int q = lane >> 4;
  float b1v[4], b2v[4];
#pragma unroll
  for (int nf = 0; nf < 4; ++nf) {
    b1v[nf] = pb1[o0 + n0 + nf * 16 + (lane & 15)];
    b2v[nf] = pb2[o0 + n0 + nf * 16 + (lane & 15)];
  }
#pragma unroll
  for (int nf = 0; nf < 4; ++nf)
#pragma unroll
    for (int rg = 0; rg < 4; ++rg) {
      size_t trow = t0 + m0 + q * 4 + rg;
      size_t col  = o0 + n0 + nf * 16 + (lane & 15);
      float v1 = acc1[nf][rg] + b1v[nf];
      float v2 = acc2[nf][rg] + b2v[nf];
      hb[trow * HID + col] = f2bf(silu_f(v1) * v2);
    }
}

// ---------------------------------------------------------------------------
// memuv body (512 thr): paths 1&2 via 256^2 8-phase core. Block covers
// [256 tok x 256 gen_w2-rows] (one u-column j, d-range [d0,d0+256)).
// Epilogue contracts vs x staged in LDS [256x256] bf16 (granule swizzle);
// leaders store float4 partials to up[p][j][t]. XCD map: bx&7 -> XCD.
// ---------------------------------------------------------------------------
union SmemUV {
  struct { unsigned short As[2 * 256 * 64], Bs[2 * 256 * 64]; } ab; // 128 KB
  struct { unsigned short Xs[256 * 256]; } ep;                      // 128 KB
};

__device__ __forceinline__ void memuv_body(
    int bx, const unsigned short* __restrict__ hgb, const float* __restrict__ gw2,
    const float* __restrict__ gen_b2, const unsigned short* __restrict__ xb,
    float* __restrict__ up, SmemUV& sm) {
  const int s8 = bx & 7, w = bx >> 3;
  const int n = s8 * 32 + (w >> 2), m = w & 3;   // n<256 (N-tile), m<4 (M-tile)
  const size_t N0 = (size_t)n * 256, t0 = (size_t)m * 256;
  const int stripA = n << 1;                     // N0>>7 (even)
  const int j  = n >> 1;                         // u column (0..127)
  const int d0 = (stripA & 3) * 128;             // {0, 256}

  f32x4 acc[8][4];
  zero_accN<8>(acc);
  mfma_256_8ph(hgb, t0, gw2, N0, sm.ab.As, sm.ab.Bs, acc);

  const int tid = threadIdx.x, lane = tid & 63, wave = tid >> 6;
  const int wr = wave >> 2, wc = wave & 3;
  // stage x tile [256 t x 256 d] bf16 with granule swizzle ^(((row>>2)&3)<<1)
#pragma unroll
  for (int i = 0; i < 16; ++i) {
    int qq = i * 512 + tid;          // 8-short granules, 8192 total
    int row = qq >> 5, c = qq & 31;
    const unsigned short* src = xb + (t0 + (size_t)row) * DIMX + d0 + c * 8;
    ushort4 v0 = *(const ushort4*)src;
    ushort4 v1 = *(const ushort4*)(src + 4);
    int cs = c ^ (((row >> 2) & 3) << 1);
    unsigned short* dst = sm.ep.Xs + row * 256 + cs * 8;
    *(ushort4*)dst = v0;
    *(ushort4*)(dst + 4) = v1;
  }
  __syncthreads();

  const int m0 = wr * 128, n0 = wc * 64;
  const int q = lane >> 4, l15 = lane & 15;
  float gbv[4];
#pragma unroll
  for (int i = 0; i < 4; ++i)
    gbv[i] = gen_b2[N0 + n0 + i * 16 + l15];

  const int p = ((stripA + (wc >> 1)) & 3) * 2 + (wc & 1);
  float* upd = up + (size_t)p * (128 * 1024) + (size_t)j * 1024 + t0;
#pragma unroll
  for (int mf = 0; mf < 8; ++mf) {
    f32x4 vals;
#pragma unroll
    for (int rg = 0; rg < 4; ++rg) {
      int trow = m0 + mf * 16 + q * 4 + rg;
      int swz  = ((trow >> 2) & 3) << 1;
      float val = 0.f;
#pragma unroll
      for (int nf = 0; nf < 4; ++nf) {
        int col = n0 + nf * 16 + l15;   // block-col 0..255 -> d = d0 + col
        int gct = col >> 3;
        int idx = trow * 256 + ((gct ^ swz) << 3) + (col & 7);
        val += (acc[mf][nf][rg] + gbv[nf]) * bf2f(sm.ep.Xs[idx]);
      }
      val += __shfl_xor(val, 1);
      val += __shfl_xor(val, 2);
      val += __shfl_xor(val, 4);
      val += __shfl_xor(val, 8);
      vals[rg] = val;
    }
    if (l15 == 0)
      *(f32x4*)(upd + m0 + mf * 16 + q * 4) = vals;
  }
}

// K2 = {memuv (1024 blocks)} ++ {ffn12 dual-tile (256 blocks)}; 512 thr.
union SmemK2 {
  SmemUV m;                                                                // 128 KB
  struct { unsigned short As[2][32 * 64], B1s[2][128 * 64], B2s[2][128 * 64]; } f; // 72 KB
};

__global__ __launch_bounds__(512, 2) void k2_kernel(
    const unsigned short* __restrict__ xb, const unsigned short* __restrict__ W1b,
    const unsigned short* __restrict__ W2b, const float* __restrict__ b1,
    const float* __restrict__ b2, unsigned short* __restrict__ hb,
    const unsigned short* __restrict__ hgb, const float* __restrict__ gw2,
    const float* __restrict__ gen_b2, float* __restrict__ up) {
  __shared__ SmemK2 sm;
  const int bx = blockIdx.x;
  if (bx < 1024) {
    memuv_body(bx, hgb, gw2, gen_b2, xb, up, sm.m);
  } else {
    const int sub = threadIdx.x >> 8, tloc = threadIdx.x & 255;
    const int vb = (bx - 1024) * 2 + sub;   // 512 virtual ffn blocks
    ffn12_body(vb, xb, W1b, W2b, b1, b2, hb,
               sm.f.As[sub], sm.f.B1s[sub], sm.f.B2s[sub], tloc);
  }
}

// ---------------------------------------------------------------------------
// gemm3p body: yp[slice] = hb @ W3b^T (partial K), 64x128 tiles.
// ---------------------------------------------------------------------------
__device__ __forceinline__ void gemm3p_body(
    int bx, const unsigned short* __restrict__ hb, const unsigned short* __restrict__ W3b,
    float* __restrict__ yp, unsigned short* As, unsigned short* Bs) {
  const int slice = bx >> 6, r6 = bx & 63;
  const int ob = r6 & 3, tb = r6 >> 2;
  const size_t o0 = (size_t)ob * 128, t0 = (size_t)tb * 64;
  const int k0 = slice * 512;
  const int tid = threadIdx.x;
  f32x4 acc[2][4];
  zero_accN<2>(acc);
  mfma_tile_nt<512, 2>(hb, t0, HID, W3b, o0, HID, k0, As, Bs, acc, tid);

  const int lane = tid & 63, wave = tid >> 6;
  const int m0 = (wave >> 1) * 32, n0 = (wave & 1) * 64;
  float* out = yp + (size_t)slice * (TOK * DIMX);
#pragma unroll
  for (int nf = 0; nf < 4; ++nf) {
    int nn = n0 + nf * 16 + (lane & 15);
#pragma unroll
    for (int mf = 0; mf < 2; ++mf) {
      int mb = m0 + mf * 16 + ((lane >> 4) << 2);
#pragma unroll
      for (int rg = 0; rg < 4; ++rg)
        out[(t0 + mb + rg) * DIMX + o0 + nn] = acc[mf][nf][rg];
    }
  }
}

// ---------------------------------------------------------------------------
// hmem body: u = sum of 8 partials; h_mem = silu(u1)*u2, [t][r].
// ---------------------------------------------------------------------------
__device__ __forceinline__ void hmem_body(int bx, const float* __restrict__ up,
                                          float* __restrict__ hm) {
  int i = bx * 256 + threadIdx.x;          // 65536
  int t = i & 1023, r = i >> 10;           // r in 0..63
  float u1 = 0.f, u2 = 0.f;
#pragma unroll
  for (int p = 0; p < 8; ++p) {
    u1 += up[(size_t)p * (128 * 1024) + (size_t)r * 1024 + t];
    u2 += up[(size_t)p * (128 * 1024) + (size_t)(64 + r) * 1024 + t];
  }
  hm[(size_t)t * RR + r] = silu_f(u1) * u2;
}

// K3 = {gemm3p (256 blocks)} ++ {hmem (256 blocks)}; 256 thr.
union SmemK3 {
  struct { unsigned short As[64 * 64], Bs[128 * 64]; } g;  // 24 KB
};

__global__ __launch_bounds__(256) void k3_kernel(
    const unsigned short* __restrict__ hb, const unsigned short* __restrict__ W3b,
    float* __restrict__ yp, const float* __restrict__ up, float* __restrict__ hm) {
  __shared__ SmemK3 sm;
  const int bx = blockIdx.x;
  if (bx < 256)
    gemm3p_body(bx, hb, W3b, yp, sm.g.As, sm.g.Bs);
  else
    hmem_body(bx - 256, up, hm);
}

// ---------------------------------------------------------------------------
// memy (512 thr): path 3 via 256^2 8-phase core. Block covers 256 tok x 256
// gen_w2-rows (= 4 output d per block, one per wave-column). Epilogue
// contracts vs h_mem in LDS [256x64] f32; single-writer y = (b3 + sum4 yp)
// + g*val. XCD map: bx&7 -> XCD.
// ---------------------------------------------------------------------------
union SmemY {
  struct { unsigned short As[2 * 256 * 64], Bs[2 * 256 * 64]; } ab;  // 128 KB
  struct { float Hs[256 * 64]; } ep;                                 // 64 KB
};

__global__ __launch_bounds__(512, 2) void memy_kernel(
    const unsigned short* __restrict__ hgb, const float* __restrict__ gw2,
    const float* __restrict__ gen_b2, const float* __restrict__ hmem,
    const float* __restrict__ yp, const float* __restrict__ b3,
    const float* __restrict__ mem_gate, float* __restrict__ y) {
  __shared__ SmemY sm;
  const int bx = blockIdx.x;
  const int s8 = bx & 7, w = bx >> 3;
  const int n = s8 * 16 + (w >> 2), m = w & 3;   // n<128, m<4
  const size_t N0 = (size_t)n * 256;
  const size_t brow0 = (size_t)O3BASE + N0;
  const size_t t0 = (size_t)m * 256;

  f32x4 acc[8][4];
  zero_accN<8>(acc);
  mfma_256_8ph(hgb, t0, gw2, brow0, sm.ab.As, sm.ab.Bs, acc);

  const int tid = threadIdx.x, lane = tid & 63, wave = tid >> 6;
  const int wr = wave >> 2, wc = wave & 3;
  // stage h_mem tile [256 t x 64 r] f32, granule swizzle ^(((row>>2)&3)<<2)
#pragma unroll
  for (int i = 0; i < 8; ++i) {
    int qq = i * 512 + tid;          // float4 granules, 4096 total
    int row = qq >> 4, c = qq & 15;
    float4 vv = *(const float4*)(hmem + (t0 + (size_t)row) * RR + c * 4);
    int cs = c ^ (((row >> 2) & 3) << 2);
    *(float4*)(sm.ep.Hs + row * 64 + cs * 4) = vv;
  }
  __syncthreads();

  const int m0 = wr * 128, n0 = wc * 64;
  const int q = lane >> 4, l15 = lane & 15;
  const float g = 1.f / (1.f + __expf(-mem_gate[0]));
  float gbv[4];
#pragma unroll
  for (int i = 0; i < 4; ++i)
    gbv[i] = gen_b2[brow0 + n0 + i * 16 + l15];

  const int d = (int)(N0 >> 6) + wc;
  const float b3v = b3[d];
#pragma unroll
  for (int mf = 0; mf < 8; ++mf)
#pragma unroll
    for (int rg = 0; rg < 4; ++rg) {
      int trow = m0 + mf * 16 + q * 4 + rg;
      int swz  = ((trow >> 2) & 3) << 2;
      float val = 0.f;
#pragma unroll
      for (int nf = 0; nf < 4; ++nf) {
        int r = nf * 16 + l15;
        int idx = trow * 64 + (((r >> 2) ^ swz) << 2) + (r & 3);
        val += (acc[mf][nf][rg] + gbv[nf]) * sm.ep.Hs[idx];
      }
      val += __shfl_xor(val, 1);
      val += __shfl_xor(val, 2);
      val += __shfl_xor(val, 4);
      val += __shfl_xor(val, 8);
      if (l15 == 0) {
        size_t gi = (t0 + trow) * DIMX + d;
        float base = b3v + yp[gi]
                   + yp[(size_t)1 * (TOK * DIMX) + gi]
                   + yp[(size_t)2 * (TOK * DIMX) + gi]
                   + yp[(size_t)3 * (TOK * DIMX) + gi];
        y[gi] = base + g * val;
      }
    }
}

// ---------------------------------------------------------------------------
extern "C" void kernel_launch(void* const* d_in, const int* in_sizes, int n_in,
                              void* d_out, int out_size, void* d_ws, size_t ws_size,
                              hipStream_t stream) {
  const float* x        = (const float*)d_in[0];
  const float* m_tok    = (const float*)d_in[1];
  const float* W1       = (const float*)d_in[2];
  const float* W2       = (const float*)d_in[3];
  const float* W3       = (const float*)d_in[4];
  const float* b1       = (const float*)d_in[5];
  const float* b2       = (const float*)d_in[6];
  const float* b3       = (const float*)d_in[7];
  const float* gen_w1   = (const float*)d_in[8];
  const float* gen_b1   = (const float*)d_in[9];
  const float* gen_w2   = (const float*)d_in[10];
  const float* gen_b2   = (const float*)d_in[11];
  const float* mem_gate = (const float*)d_in[12];
  float* y = (float*)d_out;

  char* ws = (char*)d_ws;
#define KB(v) ((size_t)(v) << 10)
  unsigned short* xb  = (unsigned short*)(ws);               // 1 MB
  unsigned short* hgb = (unsigned short*)(ws + KB(1024));    // 1 MB
  unsigned short* hb  = (unsigned short*)(ws + KB(2048));    // 4 MB
  float* up  = (float*)(ws + KB(6144));                      // 4 MB
  float* hm  = (float*)(ws + KB(10240));                     // 512 KB
  float* yp  = (float*)(ws + KB(10752));                     // 8 MB (4 slices)
  unsigned short* W1b = (unsigned short*)(ws + KB(21248));   // 2 MB
  unsigned short* W2b = (unsigned short*)(ws + KB(23296));   // 2 MB
  unsigned short* W3b = (unsigned short*)(ws + KB(25344));   // 2 MB
#undef KB

  // K1: casts + hypernet layer-1
  prep_kernel<<<256, 256, 0, stream>>>(x, m_tok, gen_w1, gen_b1, W1, W2, W3,
                                       xb, hgb, W1b, W2b, W3b);
  // K2: memory-path u/v GEMM (256^2 8-phase) + base-FFN up-proj riding along
  k2_kernel<<<1024 + 256, 512, 0, stream>>>(xb, W1b, W2b, b1, b2, hb,
                                            hgb, gen_w2, gen_b2, up);
  // K3: base-FFN down-proj partials + h_mem reduction
  k3_kernel<<<256 + 256, 256, 0, stream>>>(hb, W3b, yp, up, hm);
  // K4: path-3 GEMM (256^2 8-phase) + epilogue, yreduce folded in
  memy_kernel<<<512, 512, 0, stream>>>(hgb, gen_w2, gen_b2, hm, yp, b3,
                                       mem_gate, y);
}